// Round 1
// baseline (1460.689 us; speedup 1.0000x reference)
//
#include <hip/hip_runtime.h>
#include <math.h>

// Problem constants
constexpr int B_ = 8, C_ = 256, H_ = 64, W_ = 64;
constexpr int N_ = H_ * W_;          // 4096
constexpr int NH_ = 8, HD_ = 32;
constexpr int CM_ = 2048;
constexpr int M_ = B_ * N_;          // 32768
constexpr float EPS_ = 1e-5f;

// ---------------------------------------------------------------------------
// Transpose [B, C, N] -> [B, N, C]   (also used for conv output)
// grid (N/32, C/32, B), block (32, 8)
__global__ void transpose_cn_to_nc(const float* __restrict__ in, float* __restrict__ out) {
    __shared__ float tile[32][33];
    int b  = blockIdx.z;
    int n0 = blockIdx.x * 32;
    int c0 = blockIdx.y * 32;
    int tx = threadIdx.x;   // 0..31
    int ty = threadIdx.y;   // 0..7
    const float* src = in  + (size_t)b * C_ * N_;
    float*       dst = out + (size_t)b * N_ * C_;
#pragma unroll
    for (int i = ty; i < 32; i += 8)
        tile[i][tx] = src[(size_t)(c0 + i) * N_ + n0 + tx];
    __syncthreads();
#pragma unroll
    for (int i = ty; i < 32; i += 8)
        dst[(size_t)(n0 + i) * C_ + c0 + tx] = tile[tx][i];
}

// ---------------------------------------------------------------------------
// Simple tiled f32 GEMM: C = A[M,K] @ B[K,N] + bias, with fused epilogues.
// 64x64 tile, 256 threads, 4x4 microtile, BK=16.
// EPI 0: y = acc+bias                      -> Cout[row*N+col]
// EPI 1: z = t+y; repbn(bn1)              -> t in place   (N == C_)
// EPI 2: y = gelu_exact(acc+bias)         -> Cout[row*N+col]
// EPI 3: z = t[grow]+y; repbn(bn2); write -> out[B,C,N] transposed (N == C_)
template <int EPI>
__global__ void gemm64(const float* __restrict__ A, const float* __restrict__ Bm,
                       const float* __restrict__ bias, float* __restrict__ Cout,
                       int M, int N, int K,
                       const float* __restrict__ tres,
                       const float* __restrict__ g, const float* __restrict__ bb,
                       const float* __restrict__ m, const float* __restrict__ v,
                       const float* __restrict__ alpha, int row_off) {
    __shared__ float As[16][68];   // [k][row], padded
    __shared__ float Bs[16][64];   // [k][col]
    int tid  = threadIdx.x;
    int tx   = tid & 15, ty = tid >> 4;
    int brow = blockIdx.y * 64, bcol = blockIdx.x * 64;

    const int ar = tid >> 2;          // 0..63
    const int ac = (tid & 3) * 4;     // 0,4,8,12
    const int br = tid >> 4;          // 0..15
    const int bc = (tid & 15) * 4;    // 0..60

    float acc[4][4] = {};

    for (int k0 = 0; k0 < K; k0 += 16) {
        float4 av = *(const float4*)&A [(size_t)(brow + ar) * K + k0 + ac];
        float4 bv = *(const float4*)&Bm[(size_t)(k0 + br) * N + bcol + bc];
        As[ac + 0][ar] = av.x; As[ac + 1][ar] = av.y;
        As[ac + 2][ar] = av.z; As[ac + 3][ar] = av.w;
        *(float4*)&Bs[br][bc] = bv;
        __syncthreads();
#pragma unroll
        for (int k = 0; k < 16; ++k) {
            float4 a = *(const float4*)&As[k][ty * 4];
            float4 b = *(const float4*)&Bs[k][tx * 4];
            float aa[4] = {a.x, a.y, a.z, a.w};
            float bbv[4] = {b.x, b.y, b.z, b.w};
#pragma unroll
            for (int i = 0; i < 4; ++i)
#pragma unroll
                for (int j = 0; j < 4; ++j)
                    acc[i][j] = fmaf(aa[i], bbv[j], acc[i][j]);
        }
        __syncthreads();
    }

    float alpha_v = (EPI == 1 || EPI == 3) ? alpha[0] : 0.f;
#pragma unroll
    for (int i = 0; i < 4; ++i) {
        int row = brow + ty * 4 + i;
#pragma unroll
        for (int j = 0; j < 4; ++j) {
            int col = bcol + tx * 4 + j;
            float y = acc[i][j] + bias[col];
            if (EPI == 0) {
                Cout[(size_t)row * N + col] = y;
            } else if (EPI == 2) {
                Cout[(size_t)row * N + col] =
                    0.5f * y * (1.0f + erff(y * 0.70710678118654752f));
            } else if (EPI == 1) {
                float z = tres[(size_t)row * N + col] + y;
                float r = (z - m[col]) * rsqrtf(v[col] + EPS_) * g[col] + bb[col] + alpha_v * z;
                Cout[(size_t)row * N + col] = r;   // in-place t
            } else {  // EPI == 3
                int grow = row_off + row;
                float z = tres[(size_t)grow * C_ + col] + y;
                float r = (z - m[col]) * rsqrtf(v[col] + EPS_) * g[col] + bb[col] + alpha_v * z;
                int bi = grow >> 12;          // / N_
                int ni = grow & (N_ - 1);     // % N_
                Cout[((size_t)bi * C_ + col) * N_ + ni] = r;
            }
        }
    }
}

// ---------------------------------------------------------------------------
// ctx partials: ctxp[seg][b*NH+h][d][e] = sum_{n in seg} relu(k[n,d]) * v[n,e]
// grid (8 segs, 64 bh), block 256
__global__ void ctx_partial(const float* __restrict__ qkv, float* __restrict__ ctxp) {
    __shared__ float kb[64][32];
    __shared__ float vb[64][32];
    int seg = blockIdx.x;
    int bh  = blockIdx.y;
    int b = bh >> 3, h = bh & 7;
    int tid = threadIdx.x;
    int d  = tid >> 3;            // 0..31
    int e0 = (tid & 7) * 4;       // 0..28
    float acc[4] = {0.f, 0.f, 0.f, 0.f};
    const size_t base = (size_t)b * N_ * 768 + h * 32;
    for (int n0 = seg * 512; n0 < seg * 512 + 512; n0 += 64) {
#pragma unroll
        for (int l = 0; l < 8; ++l) {
            int flat = tid + l * 256;
            int nl = flat >> 5, dl = flat & 31;
            size_t ra = base + (size_t)(n0 + nl) * 768;
            kb[nl][dl] = qkv[ra + 256 + dl];
            vb[nl][dl] = qkv[ra + 512 + dl];
        }
        __syncthreads();
#pragma unroll
        for (int nl = 0; nl < 64; ++nl) {
            float kv = fmaxf(kb[nl][d], 0.f);
#pragma unroll
            for (int j = 0; j < 4; ++j)
                acc[j] = fmaf(kv, vb[nl][e0 + j], acc[j]);
        }
        __syncthreads();
    }
    float* o = ctxp + ((size_t)seg * 64 + bh) * 1024 + d * 32 + e0;
#pragma unroll
    for (int j = 0; j < 4; ++j) o[j] = acc[j];
}

__global__ void ctx_reduce(const float* __restrict__ ctxp, float* __restrict__ ctx) {
    int idx = blockIdx.x * 256 + threadIdx.x;  // 65536 total
    float s = 0.f;
#pragma unroll
    for (int seg = 0; seg < 8; ++seg) s += ctxp[(size_t)seg * 65536 + idx];
    ctx[idx] = s;
}

// ---------------------------------------------------------------------------
// out[b, h*32+e, n] = sum_d relu(q[n,d])*scale * ctx[bh][d][e]  (image layout)
// grid (N/64, 64 bh), block 256
__global__ void attn_out(const float* __restrict__ qkv, const float* __restrict__ ctx,
                         float* __restrict__ img) {
    __shared__ float qb[64][33];
    __shared__ float cs[32][32];
    int n0 = blockIdx.x * 64;
    int bh = blockIdx.y;
    int b = bh >> 3, h = bh & 7;
    int tid = threadIdx.x;
    const float scale = 0.17677669529663687f;  // 32^-0.5
    {   // ctx -> LDS (256 float4)
        float4 vv = ((const float4*)(ctx + (size_t)bh * 1024))[tid];
        ((float4*)&cs[0][0])[tid] = vv;
    }
    const size_t base = (size_t)b * N_ * 768 + h * 32;
#pragma unroll
    for (int l = 0; l < 8; ++l) {
        int flat = tid + l * 256;
        int nl = flat >> 5, dl = flat & 31;
        float q = qkv[base + (size_t)(n0 + nl) * 768 + dl];
        qb[nl][dl] = fmaxf(q, 0.f) * scale;
    }
    __syncthreads();
    int nl = tid & 63, ebase = tid >> 6;   // wave-uniform ebase
    float* outp = img + ((size_t)b * C_ + h * 32) * N_ + n0 + nl;
#pragma unroll
    for (int p = 0; p < 8; ++p) {
        int e = ebase + p * 4;
        float s = 0.f;
#pragma unroll
        for (int dd = 0; dd < 32; ++dd)
            s = fmaf(qb[nl][dd], cs[dd][e], s);
        outp[(size_t)e * N_] = s;
    }
}

// ---------------------------------------------------------------------------
// depthwise 3x3 SAME conv + bias, [B,C,64,64]
__global__ void dwconv3x3(const float* __restrict__ img, const float* __restrict__ w,
                          const float* __restrict__ bias, float* __restrict__ out) {
    int idx = blockIdx.x * 256 + threadIdx.x;   // B*C*N
    int x = idx & 63, y = (idx >> 6) & 63, c = (idx >> 12) & 255, b = idx >> 20;
    const float* wp = w + c * 9;
    const float* ip = img + ((size_t)b * C_ + c) * N_;
    float s = bias[c];
#pragma unroll
    for (int dy = -1; dy <= 1; ++dy) {
        int yy = y + dy;
        if (yy < 0 || yy > 63) continue;
#pragma unroll
        for (int dx = -1; dx <= 1; ++dx) {
            int xx = x + dx;
            if (xx < 0 || xx > 63) continue;
            s = fmaf(ip[yy * 64 + xx], wp[(dy + 1) * 3 + dx + 1], s);
        }
    }
    out[idx] = s;
}

// ---------------------------------------------------------------------------
extern "C" void kernel_launch(void* const* d_in, const int* in_sizes, int n_in,
                              void* d_out, int out_size, void* d_ws, size_t ws_size,
                              hipStream_t stream) {
    const float* x     = (const float*)d_in[0];
    const float* Wqkv  = (const float*)d_in[1];
    const float* bqkv  = (const float*)d_in[2];
    const float* dw_w  = (const float*)d_in[3];
    const float* dw_b  = (const float*)d_in[4];
    const float* Wproj = (const float*)d_in[5];
    const float* bproj = (const float*)d_in[6];
    const float* bn1_g = (const float*)d_in[7];
    const float* bn1_b = (const float*)d_in[8];
    const float* bn1_m = (const float*)d_in[9];
    const float* bn1_v = (const float*)d_in[10];
    const float* alpha1= (const float*)d_in[11];
    const float* Wfc1  = (const float*)d_in[12];
    const float* bfc1  = (const float*)d_in[13];
    const float* Wfc2  = (const float*)d_in[14];
    const float* bfc2  = (const float*)d_in[15];
    const float* bn2_g = (const float*)d_in[16];
    const float* bn2_b = (const float*)d_in[17];
    const float* bn2_m = (const float*)d_in[18];
    const float* bn2_v = (const float*)d_in[19];
    const float* alpha2= (const float*)d_in[20];
    float* out = (float*)d_out;

    char* ws = (char*)d_ws;
    // layout (bytes):
    //   t    @ 0          : 33,554,432   [B,N,C]  (persistent)
    //   qkv  @ 33,554,432 : 100,663,296  [B,N,768] (later reused: conv_out, convT, hidden)
    //   img  @ 134,217,728: 33,554,432   [B,C,N]
    //   ctxp @ 167,772,160:  2,097,152
    //   ctx  @ 169,869,312:    262,144
    float* t      = (float*)(ws);
    float* qkv    = (float*)(ws + 33554432);
    float* img    = (float*)(ws + 134217728);
    float* ctxp   = (float*)(ws + 167772160);
    float* ctx    = (float*)(ws + 169869312);
    float* conv_o = qkv;                          // reuse after attention
    float* convT  = (float*)(ws + 33554432 + 33554432);
    float* hidden = qkv;                          // reuse for FFN chunks (67MB)

    // 1. x [B,C,N] -> t [B,N,C]
    transpose_cn_to_nc<<<dim3(N_ / 32, C_ / 32, B_), dim3(32, 8), 0, stream>>>(x, t);

    // 2. qkv = t @ Wqkv + bqkv     [32768, 768]
    gemm64<0><<<dim3(768 / 64, M_ / 64), 256, 0, stream>>>(
        t, Wqkv, bqkv, qkv, M_, 768, C_, nullptr, nullptr, nullptr, nullptr, nullptr, nullptr, 0);

    // 3. ctx = relu(k)^T v
    ctx_partial<<<dim3(8, B_ * NH_), 256, 0, stream>>>(qkv, ctxp);
    ctx_reduce<<<256, 256, 0, stream>>>(ctxp, ctx);

    // 4. img = (relu(q)*scale) @ ctx   (written in [B,C,N] layout)
    attn_out<<<dim3(N_ / 64, B_ * NH_), 256, 0, stream>>>(qkv, ctx, img);

    // 5. depthwise conv 3x3 + bias
    dwconv3x3<<<(B_ * C_ * N_) / 256, 256, 0, stream>>>(img, dw_w, dw_b, conv_o);

    // 6. conv_out [B,C,N] -> convT [B,N,C]
    transpose_cn_to_nc<<<dim3(N_ / 32, C_ / 32, B_), dim3(32, 8), 0, stream>>>(conv_o, convT);

    // 7. t = repbn1(t + convT @ Wproj + bproj)   (in place)
    gemm64<1><<<dim3(C_ / 64, M_ / 64), 256, 0, stream>>>(
        convT, Wproj, bproj, t, M_, C_, C_, t, bn1_g, bn1_b, bn1_m, bn1_v, alpha1, 0);

    // 8. FFN in 4 chunks of 8192 rows; output fused repbn2 + transpose to d_out
    constexpr int CHUNK = 8192;
    for (int ch = 0; ch < 4; ++ch) {
        const float* Arow = t + (size_t)ch * CHUNK * C_;
        gemm64<2><<<dim3(CM_ / 64, CHUNK / 64), 256, 0, stream>>>(
            Arow, Wfc1, bfc1, hidden, CHUNK, CM_, C_, nullptr, nullptr, nullptr, nullptr,
            nullptr, nullptr, 0);
        gemm64<3><<<dim3(C_ / 64, CHUNK / 64), 256, 0, stream>>>(
            hidden, Wfc2, bfc2, out, CHUNK, C_, CM_, t, bn2_g, bn2_b, bn2_m, bn2_v,
            alpha2, ch * CHUNK);
    }
}

// Round 2
// 501.132 us; speedup vs baseline: 2.9148x; 2.9148x over previous
//
#include <hip/hip_runtime.h>
#include <hip/hip_bf16.h>
#include <math.h>

// Problem constants
constexpr int B_ = 8, C_ = 256, H_ = 64, W_ = 64;
constexpr int N_ = H_ * W_;          // 4096
constexpr int NH_ = 8;
constexpr int CM_ = 2048;
constexpr int M_ = B_ * N_;          // 32768
constexpr float EPS_ = 1e-5f;

typedef __bf16 bf16_t;
typedef bf16_t bf16x8 __attribute__((ext_vector_type(8)));
typedef float f32x4 __attribute__((ext_vector_type(4)));

__device__ inline bf16_t f2b(float f) {
    __hip_bfloat16 h = __float2bfloat16(f);
    return *reinterpret_cast<bf16_t*>(&h);
}

#define GLOAD_LDS16(gptr, lptr)                                                     \
    __builtin_amdgcn_global_load_lds(                                               \
        (const __attribute__((address_space(1))) void*)(gptr),                      \
        (__attribute__((address_space(3))) void*)(lptr), 16, 0, 0)

// ---------------------------------------------------------------------------
// Transpose [B,C,N] -> [B,N,C]. MODE 0: write f32 + bf16; MODE 1: bf16 only.
template <int MODE>
__global__ void transpose_cast(const float* __restrict__ in, float* __restrict__ outf,
                               bf16_t* __restrict__ outb) {
    __shared__ float tile[32][33];
    int b  = blockIdx.z;
    int n0 = blockIdx.x * 32;
    int c0 = blockIdx.y * 32;
    int tx = threadIdx.x, ty = threadIdx.y;
    const float* src = in + (size_t)b * C_ * N_;
#pragma unroll
    for (int i = ty; i < 32; i += 8)
        tile[i][tx] = src[(size_t)(c0 + i) * N_ + n0 + tx];
    __syncthreads();
#pragma unroll
    for (int i = ty; i < 32; i += 8) {
        float v = tile[tx][i];
        size_t off = (size_t)b * N_ * C_ + (size_t)(n0 + i) * C_ + c0 + tx;
        if (MODE == 0) outf[off] = v;
        outb[off] = f2b(v);
    }
}

// ---------------------------------------------------------------------------
// Weight cast + transpose: W [K,N] f32 -> Wt [N,K] bf16
__global__ void wcastT(const float* __restrict__ W, bf16_t* __restrict__ Wt,
                       int K, int N) {
    __shared__ float tile[32][33];
    int k0 = blockIdx.y * 32, n0 = blockIdx.x * 32;
    int tx = threadIdx.x, ty = threadIdx.y;
#pragma unroll
    for (int i = ty; i < 32; i += 8)
        tile[i][tx] = W[(size_t)(k0 + i) * N + n0 + tx];
    __syncthreads();
#pragma unroll
    for (int i = ty; i < 32; i += 8)
        Wt[(size_t)(n0 + i) * K + k0 + tx] = f2b(tile[tx][i]);
}

// ---------------------------------------------------------------------------
// bf16 MFMA GEMM: C = A[M,K] @ Bt[N,K]^T + bias, fused epilogues.
// 128x128 tile, BK=64, 4 waves (each 64x64 out via 4x4 frags of 16x16x32).
// LDS is fragment-linear: instr jj (msub 0..7, khalf 0..1) occupies 1KB;
// within: lane l -> row l&15, kq l>>4 -> frag read = contiguous b128.
// EPI 0: Cf = acc+bias                               (f32)
// EPI 1: z=tres+acc+bias; repbn1 -> Cf (f32, in-place t) AND Cb (bf16)
// EPI 2: gelu_exact(acc+bias) -> Cb (bf16)
// EPI 3: z=tres[grow]+acc+bias; repbn2 -> Cf transposed to [B,C,N] (f32)
template <int EPI>
__global__ __launch_bounds__(256)
void gemm_bf16(const bf16_t* __restrict__ A, const bf16_t* __restrict__ Bt,
               const float* __restrict__ bias,
               float* __restrict__ Cf, bf16_t* __restrict__ Cb,
               int M, int N, int K,
               const float* __restrict__ tres,
               const float* __restrict__ g, const float* __restrict__ bb,
               const float* __restrict__ mm, const float* __restrict__ vv,
               const float* __restrict__ alpha, int row_off) {
    __shared__ bf16x8 ldsv[2048];          // 32 KB: A = [0,1024), B = [1024,2048)
    char* lds = (char*)ldsv;

    int tid  = threadIdx.x;
    int lane = tid & 63;
    int w    = tid >> 6;                    // wave 0..3
    int wm   = w >> 1, wn = w & 1;          // 2x2 wave grid
    int brow = blockIdx.y * 128, bcol = blockIdx.x * 128;
    int rowl = lane & 15, kq = lane >> 4;

    f32x4 acc[4][4] = {};

    for (int k0 = 0; k0 < K; k0 += 64) {
#pragma unroll
        for (int j = 0; j < 4; ++j) {
            int jj = w * 4 + j;             // 0..15
            int msub = jj >> 1, kh = jj & 1;
            const bf16_t* ga = A + ((size_t)(brow + msub * 16 + rowl) * K + k0 + kh * 32 + kq * 8);
            GLOAD_LDS16(ga, lds + jj * 1024);
            const bf16_t* gb = Bt + ((size_t)(bcol + msub * 16 + rowl) * K + k0 + kh * 32 + kq * 8);
            GLOAD_LDS16(gb, lds + 16384 + jj * 1024);
        }
        __syncthreads();
#pragma unroll
        for (int ks = 0; ks < 2; ++ks) {
            bf16x8 af[4], bf[4];
#pragma unroll
            for (int m = 0; m < 4; ++m) af[m] = ldsv[((wm * 4 + m) * 2 + ks) * 64 + lane];
#pragma unroll
            for (int n = 0; n < 4; ++n) bf[n] = ldsv[1024 + ((wn * 4 + n) * 2 + ks) * 64 + lane];
#pragma unroll
            for (int m = 0; m < 4; ++m)
#pragma unroll
                for (int n = 0; n < 4; ++n)
                    acc[m][n] = __builtin_amdgcn_mfma_f32_16x16x32_bf16(af[m], bf[n], acc[m][n], 0, 0, 0);
        }
        __syncthreads();
    }

    float alpha_v = (EPI == 1 || EPI == 3) ? alpha[0] : 0.f;
#pragma unroll
    for (int m = 0; m < 4; ++m) {
#pragma unroll
        for (int n = 0; n < 4; ++n) {
            int col = bcol + wn * 64 + n * 16 + (lane & 15);
            float bv = bias[col];
#pragma unroll
            for (int r = 0; r < 4; ++r) {
                int row = brow + wm * 64 + m * 16 + (lane >> 4) * 4 + r;
                float y = acc[m][n][r] + bv;
                if (EPI == 0) {
                    Cf[(size_t)row * N + col] = y;
                } else if (EPI == 2) {
                    float ge = 0.5f * y * (1.0f + erff(y * 0.70710678118654752f));
                    Cb[(size_t)row * N + col] = f2b(ge);
                } else if (EPI == 1) {
                    float z = tres[(size_t)row * N + col] + y;
                    float rr = (z - mm[col]) * rsqrtf(vv[col] + EPS_) * g[col] + bb[col] + alpha_v * z;
                    Cf[(size_t)row * N + col] = rr;
                    Cb[(size_t)row * N + col] = f2b(rr);
                } else {  // EPI 3
                    int grow = row_off + row;
                    float z = tres[(size_t)grow * C_ + col] + y;
                    float rr = (z - mm[col]) * rsqrtf(vv[col] + EPS_) * g[col] + bb[col] + alpha_v * z;
                    int bi = grow >> 12, ni = grow & (N_ - 1);
                    Cf[((size_t)bi * C_ + col) * N_ + ni] = rr;
                }
            }
        }
    }
}

// ---------------------------------------------------------------------------
// ctx partials: ctxp[seg][b*NH+h][d][e] = sum_{n in seg} relu(k[n,d]) * v[n,e]
__global__ void ctx_partial(const float* __restrict__ qkv, float* __restrict__ ctxp) {
    __shared__ float kb[64][32];
    __shared__ float vb[64][32];
    int seg = blockIdx.x;
    int bh  = blockIdx.y;
    int b = bh >> 3, h = bh & 7;
    int tid = threadIdx.x;
    int d  = tid >> 3;
    int e0 = (tid & 7) * 4;
    float acc[4] = {0.f, 0.f, 0.f, 0.f};
    const size_t base = (size_t)b * N_ * 768 + h * 32;
    for (int n0 = seg * 512; n0 < seg * 512 + 512; n0 += 64) {
#pragma unroll
        for (int l = 0; l < 8; ++l) {
            int flat = tid + l * 256;
            int nl = flat >> 5, dl = flat & 31;
            size_t ra = base + (size_t)(n0 + nl) * 768;
            kb[nl][dl] = qkv[ra + 256 + dl];
            vb[nl][dl] = qkv[ra + 512 + dl];
        }
        __syncthreads();
#pragma unroll
        for (int nl = 0; nl < 64; ++nl) {
            float kv = fmaxf(kb[nl][d], 0.f);
#pragma unroll
            for (int j = 0; j < 4; ++j)
                acc[j] = fmaf(kv, vb[nl][e0 + j], acc[j]);
        }
        __syncthreads();
    }
    float* o = ctxp + ((size_t)seg * 64 + bh) * 1024 + d * 32 + e0;
#pragma unroll
    for (int j = 0; j < 4; ++j) o[j] = acc[j];
}

__global__ void ctx_reduce(const float* __restrict__ ctxp, float* __restrict__ ctx) {
    int idx = blockIdx.x * 256 + threadIdx.x;
    float s = 0.f;
#pragma unroll
    for (int seg = 0; seg < 8; ++seg) s += ctxp[(size_t)seg * 65536 + idx];
    ctx[idx] = s;
}

// ---------------------------------------------------------------------------
__global__ void attn_out(const float* __restrict__ qkv, const float* __restrict__ ctx,
                         float* __restrict__ img) {
    __shared__ float qb[64][33];
    __shared__ float cs[32][32];
    int n0 = blockIdx.x * 64;
    int bh = blockIdx.y;
    int b = bh >> 3, h = bh & 7;
    int tid = threadIdx.x;
    const float scale = 0.17677669529663687f;
    {
        float4 vv = ((const float4*)(ctx + (size_t)bh * 1024))[tid];
        ((float4*)&cs[0][0])[tid] = vv;
    }
    const size_t base = (size_t)b * N_ * 768 + h * 32;
#pragma unroll
    for (int l = 0; l < 8; ++l) {
        int flat = tid + l * 256;
        int nl = flat >> 5, dl = flat & 31;
        float q = qkv[base + (size_t)(n0 + nl) * 768 + dl];
        qb[nl][dl] = fmaxf(q, 0.f) * scale;
    }
    __syncthreads();
    int nl = tid & 63, ebase = tid >> 6;
    float* outp = img + ((size_t)b * C_ + h * 32) * N_ + n0 + nl;
#pragma unroll
    for (int p = 0; p < 8; ++p) {
        int e = ebase + p * 4;
        float s = 0.f;
#pragma unroll
        for (int dd = 0; dd < 32; ++dd)
            s = fmaf(qb[nl][dd], cs[dd][e], s);
        outp[(size_t)e * N_] = s;
    }
}

// ---------------------------------------------------------------------------
__global__ void dwconv3x3(const float* __restrict__ img, const float* __restrict__ w,
                          const float* __restrict__ bias, float* __restrict__ out) {
    int idx = blockIdx.x * 256 + threadIdx.x;
    int x = idx & 63, y = (idx >> 6) & 63, c = (idx >> 12) & 255, b = idx >> 20;
    const float* wp = w + c * 9;
    const float* ip = img + ((size_t)b * C_ + c) * N_;
    float s = bias[c];
#pragma unroll
    for (int dy = -1; dy <= 1; ++dy) {
        int yy = y + dy;
        if (yy < 0 || yy > 63) continue;
#pragma unroll
        for (int dx = -1; dx <= 1; ++dx) {
            int xx = x + dx;
            if (xx < 0 || xx > 63) continue;
            s = fmaf(ip[yy * 64 + xx], wp[(dy + 1) * 3 + dx + 1], s);
        }
    }
    out[idx] = s;
}

// ---------------------------------------------------------------------------
extern "C" void kernel_launch(void* const* d_in, const int* in_sizes, int n_in,
                              void* d_out, int out_size, void* d_ws, size_t ws_size,
                              hipStream_t stream) {
    const float* x     = (const float*)d_in[0];
    const float* Wqkv  = (const float*)d_in[1];
    const float* bqkv  = (const float*)d_in[2];
    const float* dw_w  = (const float*)d_in[3];
    const float* dw_b  = (const float*)d_in[4];
    const float* Wproj = (const float*)d_in[5];
    const float* bproj = (const float*)d_in[6];
    const float* bn1_g = (const float*)d_in[7];
    const float* bn1_b = (const float*)d_in[8];
    const float* bn1_m = (const float*)d_in[9];
    const float* bn1_v = (const float*)d_in[10];
    const float* alpha1= (const float*)d_in[11];
    const float* Wfc1  = (const float*)d_in[12];
    const float* bfc1  = (const float*)d_in[13];
    const float* Wfc2  = (const float*)d_in[14];
    const float* bfc2  = (const float*)d_in[15];
    const float* bn2_g = (const float*)d_in[16];
    const float* bn2_b = (const float*)d_in[17];
    const float* bn2_m = (const float*)d_in[18];
    const float* bn2_v = (const float*)d_in[19];
    const float* alpha2= (const float*)d_in[20];
    float* out = (float*)d_out;

    char* ws = (char*)d_ws;
    // Workspace layout (bytes), total 170,000,384 <= proven 170,131,456:
    //   t       @ 0           33,554,432  f32 [B,N,C]        (ph1..ph9)
    //   qkv     @ 33,554,432  100,663,296 f32 [B,N,768]      (ph2..ph4)
    //   t_b     @ 134,217,728 16,777,216  bf16 [B,N,C]       (ph1..ph2)
    //   WqkvT   @ 150,994,944 393,216     bf16 [768,256]     (ph1.5..ph2)
    //   img     @ 134,217,728 33,554,432  f32 [B,C,N]        (ph4..ph5)
    //   ctxp    @ 167,772,160 2,097,152                      (ph3)
    //   ctx     @ 169,869,312 262,144                        (ph3..ph4)
    //   conv_o  @ 33,554,432  33,554,432  f32 [B,C,N]        (ph5..ph6)
    //   convT_b @ 67,108,864  16,777,216  bf16 [B,N,C]       (ph6..ph7)
    //   WprojT  @ 83,886,080  131,072     bf16 [256,256]     (ph6.5..ph7)
    //   t_b2    @ 84,017,152  16,777,216  bf16 [B,N,C]       (ph7..ph8)
    //   Wfc1T   @ 100,794,368 1,048,576   bf16 [2048,256]    (ph6.5..ph8)
    //   Wfc2T   @ 101,842,944 1,048,576   bf16 [256,2048]    (ph6.5..ph9)
    //   hidden  @ 102,891,520 67,108,864  bf16 [16384,2048]  (ph8..ph9, per chunk)
    float*  t       = (float*)(ws);
    float*  qkv     = (float*)(ws + 33554432);
    bf16_t* t_b     = (bf16_t*)(ws + 134217728);
    bf16_t* WqkvT   = (bf16_t*)(ws + 150994944);
    float*  img     = (float*)(ws + 134217728);
    float*  ctxp    = (float*)(ws + 167772160);
    float*  ctx     = (float*)(ws + 169869312);
    float*  conv_o  = (float*)(ws + 33554432);
    bf16_t* convT_b = (bf16_t*)(ws + 67108864);
    bf16_t* WprojT  = (bf16_t*)(ws + 83886080);
    bf16_t* t_b2    = (bf16_t*)(ws + 84017152);
    bf16_t* Wfc1T   = (bf16_t*)(ws + 100794368);
    bf16_t* Wfc2T   = (bf16_t*)(ws + 101842944);
    bf16_t* hidden  = (bf16_t*)(ws + 102891520);

    // ph1: x -> t (f32) + t_b (bf16)
    transpose_cast<0><<<dim3(N_ / 32, C_ / 32, B_), dim3(32, 8), 0, stream>>>(x, t, t_b);
    // ph1.5: Wqkv -> WqkvT bf16
    wcastT<<<dim3(768 / 32, C_ / 32), dim3(32, 8), 0, stream>>>(Wqkv, WqkvT, C_, 768);

    // ph2: qkv = t @ Wqkv + bqkv (f32 out)
    gemm_bf16<0><<<dim3(768 / 128, M_ / 128), 256, 0, stream>>>(
        t_b, WqkvT, bqkv, qkv, nullptr, M_, 768, C_,
        nullptr, nullptr, nullptr, nullptr, nullptr, nullptr, 0);

    // ph3: ctx = relu(k)^T v
    ctx_partial<<<dim3(8, B_ * NH_), 256, 0, stream>>>(qkv, ctxp);
    ctx_reduce<<<256, 256, 0, stream>>>(ctxp, ctx);

    // ph4: img = (relu(q)*scale) @ ctx   [B,C,N]
    attn_out<<<dim3(N_ / 64, B_ * NH_), 256, 0, stream>>>(qkv, ctx, img);

    // ph5: depthwise conv
    dwconv3x3<<<(B_ * C_ * N_) / 256, 256, 0, stream>>>(img, dw_w, dw_b, conv_o);

    // ph6: conv_o -> convT_b (bf16 [B,N,C])
    transpose_cast<1><<<dim3(N_ / 32, C_ / 32, B_), dim3(32, 8), 0, stream>>>(conv_o, nullptr, convT_b);

    // ph6.5: remaining weights -> bf16 transposed
    wcastT<<<dim3(C_ / 32, C_ / 32), dim3(32, 8), 0, stream>>>(Wproj, WprojT, C_, C_);
    wcastT<<<dim3(CM_ / 32, C_ / 32), dim3(32, 8), 0, stream>>>(Wfc1, Wfc1T, C_, CM_);
    wcastT<<<dim3(C_ / 32, CM_ / 32), dim3(32, 8), 0, stream>>>(Wfc2, Wfc2T, CM_, C_);

    // ph7: t = repbn1(t + convT @ Wproj + bproj); also t_b2 = bf16(t)
    gemm_bf16<1><<<dim3(C_ / 128, M_ / 128), 256, 0, stream>>>(
        convT_b, WprojT, bproj, t, t_b2, M_, C_, C_,
        t, bn1_g, bn1_b, bn1_m, bn1_v, alpha1, 0);

    // ph8/ph9: FFN in 2 chunks of 16384 rows
    constexpr int CHUNK = 16384;
    for (int ch = 0; ch < 2; ++ch) {
        const bf16_t* Arow = t_b2 + (size_t)ch * CHUNK * C_;
        gemm_bf16<2><<<dim3(CM_ / 128, CHUNK / 128), 256, 0, stream>>>(
            Arow, Wfc1T, bfc1, nullptr, hidden, CHUNK, CM_, C_,
            nullptr, nullptr, nullptr, nullptr, nullptr, nullptr, 0);
        gemm_bf16<3><<<dim3(C_ / 128, CHUNK / 128), 256, 0, stream>>>(
            hidden, Wfc2T, bfc2, out, nullptr, CHUNK, C_, CM_,
            t, bn2_g, bn2_b, bn2_m, bn2_v, alpha2, ch * CHUNK);
    }
}

// Round 3
// 415.052 us; speedup vs baseline: 3.5193x; 1.2074x over previous
//
#include <hip/hip_runtime.h>
#include <hip/hip_bf16.h>
#include <math.h>

// Problem constants
constexpr int B_ = 8, C_ = 256, H_ = 64, W_ = 64;
constexpr int N_ = H_ * W_;          // 4096
constexpr int NH_ = 8;
constexpr int CM_ = 2048;
constexpr int M_ = B_ * N_;          // 32768
constexpr float EPS_ = 1e-5f;

typedef __bf16 bf16_t;
typedef bf16_t bf16x8 __attribute__((ext_vector_type(8)));
typedef float f32x4 __attribute__((ext_vector_type(4)));

__device__ inline bf16_t f2b(float f) {
    __hip_bfloat16 h = __float2bfloat16(f);
    return *reinterpret_cast<bf16_t*>(&h);
}
__device__ inline float b2f(bf16_t b) {
    unsigned short u = *reinterpret_cast<unsigned short*>(&b);
    unsigned int x = (unsigned int)u << 16;
    return *reinterpret_cast<float*>(&x);
}

#define GLOAD_LDS16(gptr, lptr)                                                     \
    __builtin_amdgcn_global_load_lds(                                               \
        (const __attribute__((address_space(1))) void*)(gptr),                      \
        (__attribute__((address_space(3))) void*)(lptr), 16, 0, 0)

// ---------------------------------------------------------------------------
// Transpose [B,C,N] -> [B,N,C].
// MODE 0: f32 in -> f32 out + bf16 out;  MODE 1: bf16 in -> bf16 out.
template <int MODE>
__global__ void transpose_cast(const void* __restrict__ in_, float* __restrict__ outf,
                               bf16_t* __restrict__ outb) {
    __shared__ float tile[32][33];
    int b  = blockIdx.z;
    int n0 = blockIdx.x * 32;
    int c0 = blockIdx.y * 32;
    int tx = threadIdx.x, ty = threadIdx.y;
#pragma unroll
    for (int i = ty; i < 32; i += 8) {
        size_t off = (size_t)b * C_ * N_ + (size_t)(c0 + i) * N_ + n0 + tx;
        tile[i][tx] = (MODE == 0) ? ((const float*)in_)[off] : b2f(((const bf16_t*)in_)[off]);
    }
    __syncthreads();
#pragma unroll
    for (int i = ty; i < 32; i += 8) {
        float v = tile[tx][i];
        size_t off = (size_t)b * N_ * C_ + (size_t)(n0 + i) * C_ + c0 + tx;
        if (MODE == 0) outf[off] = v;
        outb[off] = f2b(v);
    }
}

// ---------------------------------------------------------------------------
// Weight cast + transpose: W [K,N] f32 -> Wt [N,K] bf16
__global__ void wcastT(const float* __restrict__ W, bf16_t* __restrict__ Wt,
                       int K, int N) {
    __shared__ float tile[32][33];
    int k0 = blockIdx.y * 32, n0 = blockIdx.x * 32;
    int tx = threadIdx.x, ty = threadIdx.y;
#pragma unroll
    for (int i = ty; i < 32; i += 8)
        tile[i][tx] = W[(size_t)(k0 + i) * N + n0 + tx];
    __syncthreads();
#pragma unroll
    for (int i = ty; i < 32; i += 8)
        Wt[(size_t)(n0 + i) * K + k0 + tx] = f2b(tile[tx][i]);
}

// ---------------------------------------------------------------------------
// bf16 MFMA GEMM: C = A[M,K] @ Bt[N,K]^T + bias, fused epilogues.
// 128x128 tile, BK=64, 4 waves (each 64x64 out via 4x4 frags of 16x16x32).
// EPI 0: acc+bias -> Cf (f32)
// EPI 1: z=tres+acc+bias; repbn1 -> Cf (f32, in-place t) AND Cb (bf16)
// EPI 2: gelu_approx(acc+bias) -> Cb (bf16)
// EPI 3: z=tres[grow]+acc+bias; repbn2 -> Cf transposed to [B,C,N] (f32)
// EPI 4: acc+bias -> Cb (bf16)
template <int EPI>
__global__ __launch_bounds__(256)
void gemm_bf16(const bf16_t* __restrict__ A, const bf16_t* __restrict__ Bt,
               const float* __restrict__ bias,
               float* __restrict__ Cf, bf16_t* __restrict__ Cb,
               int M, int N, int K,
               const float* __restrict__ tres,
               const float* __restrict__ g, const float* __restrict__ bb,
               const float* __restrict__ mm, const float* __restrict__ vv,
               const float* __restrict__ alpha, int row_off) {
    __shared__ bf16x8 ldsv[2048];          // 32 KB: A = [0,1024), B = [1024,2048)
    char* lds = (char*)ldsv;

    int tid  = threadIdx.x;
    int lane = tid & 63;
    int w    = tid >> 6;
    int wm   = w >> 1, wn = w & 1;
    int brow = blockIdx.y * 128, bcol = blockIdx.x * 128;
    int rowl = lane & 15, kq = lane >> 4;

    f32x4 acc[4][4] = {};

    for (int k0 = 0; k0 < K; k0 += 64) {
#pragma unroll
        for (int j = 0; j < 4; ++j) {
            int jj = w * 4 + j;
            int msub = jj >> 1, kh = jj & 1;
            const bf16_t* ga = A + ((size_t)(brow + msub * 16 + rowl) * K + k0 + kh * 32 + kq * 8);
            GLOAD_LDS16(ga, lds + jj * 1024);
            const bf16_t* gb = Bt + ((size_t)(bcol + msub * 16 + rowl) * K + k0 + kh * 32 + kq * 8);
            GLOAD_LDS16(gb, lds + 16384 + jj * 1024);
        }
        __syncthreads();
#pragma unroll
        for (int ks = 0; ks < 2; ++ks) {
            bf16x8 af[4], bfr[4];
#pragma unroll
            for (int m = 0; m < 4; ++m) af[m] = ldsv[((wm * 4 + m) * 2 + ks) * 64 + lane];
#pragma unroll
            for (int n = 0; n < 4; ++n) bfr[n] = ldsv[1024 + ((wn * 4 + n) * 2 + ks) * 64 + lane];
#pragma unroll
            for (int m = 0; m < 4; ++m)
#pragma unroll
                for (int n = 0; n < 4; ++n)
                    acc[m][n] = __builtin_amdgcn_mfma_f32_16x16x32_bf16(af[m], bfr[n], acc[m][n], 0, 0, 0);
        }
        __syncthreads();
    }

    float alpha_v = (EPI == 1 || EPI == 3) ? alpha[0] : 0.f;
#pragma unroll
    for (int m = 0; m < 4; ++m) {
#pragma unroll
        for (int n = 0; n < 4; ++n) {
            int col = bcol + wn * 64 + n * 16 + (lane & 15);
            float bv = bias[col];
#pragma unroll
            for (int r = 0; r < 4; ++r) {
                int row = brow + wm * 64 + m * 16 + (lane >> 4) * 4 + r;
                float y = acc[m][n][r] + bv;
                if (EPI == 0) {
                    Cf[(size_t)row * N + col] = y;
                } else if (EPI == 4) {
                    Cb[(size_t)row * N + col] = f2b(y);
                } else if (EPI == 2) {
                    // gelu(y) ~= y - y / (exp(2u)+1), u = y*(c1 + c3*y^2)
                    float u = y * (0.7978845608f + 0.0356774081f * y * y);
                    float e = __expf(2.0f * u);
                    float ge = y - y * __builtin_amdgcn_rcpf(e + 1.0f);
                    Cb[(size_t)row * N + col] = f2b(ge);
                } else if (EPI == 1) {
                    float z = tres[(size_t)row * N + col] + y;
                    float rr = (z - mm[col]) * rsqrtf(vv[col] + EPS_) * g[col] + bb[col] + alpha_v * z;
                    Cf[(size_t)row * N + col] = rr;
                    Cb[(size_t)row * N + col] = f2b(rr);
                } else {  // EPI 3
                    int grow = row_off + row;
                    float z = tres[(size_t)grow * C_ + col] + y;
                    float rr = (z - mm[col]) * rsqrtf(vv[col] + EPS_) * g[col] + bb[col] + alpha_v * z;
                    int bi = grow >> 12, ni = grow & (N_ - 1);
                    Cf[((size_t)bi * C_ + col) * N_ + ni] = rr;
                }
            }
        }
    }
}

// ---------------------------------------------------------------------------
// ctx partials: ctxp[seg][b*NH+h][d][e] = sum_{n in seg} relu(k[n,d]) * v[n,e]
// qkv is bf16 [B,N,768]
__global__ void ctx_partial(const bf16_t* __restrict__ qkv, float* __restrict__ ctxp) {
    __shared__ float kb[64][40];
    __shared__ float vb[64][40];
    int seg = blockIdx.x;
    int bh  = blockIdx.y;
    int b = bh >> 3, h = bh & 7;
    int tid = threadIdx.x;
    int d  = tid >> 3;
    int e0 = (tid & 7) * 4;
    int lrow = tid >> 2, lcol = (tid & 3) * 8;
    float acc[4] = {0.f, 0.f, 0.f, 0.f};
    const size_t base = (size_t)b * N_ * 768 + h * 32;
    for (int n0 = seg * 512; n0 < seg * 512 + 512; n0 += 64) {
        size_t ra = base + (size_t)(n0 + lrow) * 768 + lcol;
        bf16x8 kv8 = *(const bf16x8*)(qkv + ra + 256);
        bf16x8 vv8 = *(const bf16x8*)(qkv + ra + 512);
#pragma unroll
        for (int j = 0; j < 8; ++j) {
            kb[lrow][lcol + j] = b2f(kv8[j]);
            vb[lrow][lcol + j] = b2f(vv8[j]);
        }
        __syncthreads();
#pragma unroll
        for (int nl = 0; nl < 64; ++nl) {
            float kv = fmaxf(kb[nl][d], 0.f);
#pragma unroll
            for (int j = 0; j < 4; ++j)
                acc[j] = fmaf(kv, vb[nl][e0 + j], acc[j]);
        }
        __syncthreads();
    }
    float* o = ctxp + ((size_t)seg * 64 + bh) * 1024 + d * 32 + e0;
#pragma unroll
    for (int j = 0; j < 4; ++j) o[j] = acc[j];
}

__global__ void ctx_reduce(const float* __restrict__ ctxp, float* __restrict__ ctx) {
    int idx = blockIdx.x * 256 + threadIdx.x;
    float s = 0.f;
#pragma unroll
    for (int seg = 0; seg < 8; ++seg) s += ctxp[(size_t)seg * 65536 + idx];
    ctx[idx] = s;
}

// ---------------------------------------------------------------------------
// img[b, h*32+e, n] = sum_d relu(q[n,d])*scale * ctx[bh][d][e]   (bf16 out)
__global__ void attn_out(const bf16_t* __restrict__ qkv, const float* __restrict__ ctx,
                         bf16_t* __restrict__ img) {
    __shared__ float qb[64][33];
    __shared__ float cs[32][32];
    int n0 = blockIdx.x * 64;
    int bh = blockIdx.y;
    int b = bh >> 3, h = bh & 7;
    int tid = threadIdx.x;
    const float scale = 0.17677669529663687f;
    {
        float4 vv = ((const float4*)(ctx + (size_t)bh * 1024))[tid];
        ((float4*)&cs[0][0])[tid] = vv;
    }
    const size_t base = (size_t)b * N_ * 768 + h * 32;
    int lrow = tid >> 2, lcol = (tid & 3) * 8;
    {
        bf16x8 q8 = *(const bf16x8*)(qkv + base + (size_t)(n0 + lrow) * 768 + lcol);
#pragma unroll
        for (int j = 0; j < 8; ++j)
            qb[lrow][lcol + j] = fmaxf(b2f(q8[j]), 0.f) * scale;
    }
    __syncthreads();
    int nl = tid & 63, ebase = tid >> 6;
    bf16_t* outp = img + ((size_t)b * C_ + h * 32) * N_ + n0 + nl;
#pragma unroll
    for (int p = 0; p < 8; ++p) {
        int e = ebase + p * 4;
        float s = 0.f;
#pragma unroll
        for (int dd = 0; dd < 32; ++dd)
            s = fmaf(qb[nl][dd], cs[dd][e], s);
        outp[(size_t)e * N_] = f2b(s);
    }
}

// ---------------------------------------------------------------------------
// depthwise 3x3 SAME conv + bias. One block per (b,c) plane (64x64), bf16 io.
__global__ __launch_bounds__(256)
void dwconv3x3(const bf16_t* __restrict__ img, const float* __restrict__ w,
               const float* __restrict__ bias, bf16_t* __restrict__ out) {
    __shared__ float sp[64][65];
    int bc = blockIdx.x;            // b*C + c
    int c  = bc & 255;
    int tid = threadIdx.x;
    const bf16_t* ip = img + (size_t)bc * N_;
    // stage plane
#pragma unroll
    for (int l = 0; l < 2; ++l) {
        int flat = (tid + l * 256) * 8;
        int row = flat >> 6, col = flat & 63;
        bf16x8 v8 = *(const bf16x8*)(ip + flat);
#pragma unroll
        for (int j = 0; j < 8; ++j) sp[row][col + j] = b2f(v8[j]);
    }
    float wv[9];
#pragma unroll
    for (int j = 0; j < 9; ++j) wv[j] = w[c * 9 + j];
    float bv = bias[c];
    __syncthreads();

    int y = tid >> 2, x0 = (tid & 3) * 16;
    float o[16];
#pragma unroll
    for (int i = 0; i < 16; ++i) o[i] = bv;
#pragma unroll
    for (int dy = -1; dy <= 1; ++dy) {
        int yy = y + dy;
        if (yy < 0 || yy > 63) continue;
#pragma unroll
        for (int dx = -1; dx <= 1; ++dx) {
            float wgt = wv[(dy + 1) * 3 + dx + 1];
#pragma unroll
            for (int i = 0; i < 16; ++i) {
                int xx = x0 + i + dx;
                float val = (xx < 0 || xx > 63) ? 0.f : sp[yy][xx];
                o[i] = fmaf(wgt, val, o[i]);
            }
        }
    }
    bf16_t ob[16];
#pragma unroll
    for (int i = 0; i < 16; ++i) ob[i] = f2b(o[i]);
    *(bf16x8*)(out + (size_t)bc * N_ + y * 64 + x0)     = *(bf16x8*)&ob[0];
    *(bf16x8*)(out + (size_t)bc * N_ + y * 64 + x0 + 8) = *(bf16x8*)&ob[8];
}

// ---------------------------------------------------------------------------
extern "C" void kernel_launch(void* const* d_in, const int* in_sizes, int n_in,
                              void* d_out, int out_size, void* d_ws, size_t ws_size,
                              hipStream_t stream) {
    const float* x     = (const float*)d_in[0];
    const float* Wqkv  = (const float*)d_in[1];
    const float* bqkv  = (const float*)d_in[2];
    const float* dw_w  = (const float*)d_in[3];
    const float* dw_b  = (const float*)d_in[4];
    const float* Wproj = (const float*)d_in[5];
    const float* bproj = (const float*)d_in[6];
    const float* bn1_g = (const float*)d_in[7];
    const float* bn1_b = (const float*)d_in[8];
    const float* bn1_m = (const float*)d_in[9];
    const float* bn1_v = (const float*)d_in[10];
    const float* alpha1= (const float*)d_in[11];
    const float* Wfc1  = (const float*)d_in[12];
    const float* bfc1  = (const float*)d_in[13];
    const float* Wfc2  = (const float*)d_in[14];
    const float* bfc2  = (const float*)d_in[15];
    const float* bn2_g = (const float*)d_in[16];
    const float* bn2_b = (const float*)d_in[17];
    const float* bn2_m = (const float*)d_in[18];
    const float* bn2_v = (const float*)d_in[19];
    const float* alpha2= (const float*)d_in[20];
    float* out = (float*)d_out;

    char* ws = (char*)d_ws;
    // Workspace layout (bytes), max 155,975,680 <= proven 170,131,456:
    //   t       @ 0           33,554,432  f32 [B,N,C]       (ph1..ph9)
    //   qkv_b   @ 33,554,432  50,331,648  bf16 [B,N,768]    (ph2..ph4)
    //   convT_b @ 83,886,080  16,777,216  bf16 [B,N,C]      (ph6..ph7)  (over dead t_b)
    //   t_b     @ 83,886,080  16,777,216  bf16 [B,N,C]      (ph1..ph2)
    //   t_b2    @ 100,663,296 16,777,216  bf16 [B,N,C]      (ph7..ph9)
    //   hidden  @ 33,554,432  67,108,864  bf16 [16384,2048] (ph8..ph9; over dead qkv_b+convT_b)
    //   img_b   @ 117,440,512 16,777,216  bf16 [B,C,N]      (ph4..ph5)
    //   conv_b  @ 134,217,728 16,777,216  bf16 [B,C,N]      (ph5..ph6)
    //   ctxp    @ 150,994,944  2,097,152                    (ph3)
    //   ctx     @ 153,092,096    262,144                    (ph3..ph4)
    //   WqkvT   @ 153,354,240    393,216  bf16
    //   WprojT  @ 153,747,456    131,072  bf16
    //   Wfc1T   @ 153,878,528  1,048,576  bf16
    //   Wfc2T   @ 154,927,104  1,048,576  bf16
    float*  t       = (float*)(ws);
    bf16_t* qkv_b   = (bf16_t*)(ws + 33554432);
    bf16_t* t_b     = (bf16_t*)(ws + 83886080);
    bf16_t* convT_b = (bf16_t*)(ws + 83886080);
    bf16_t* t_b2    = (bf16_t*)(ws + 100663296);
    bf16_t* hidden  = (bf16_t*)(ws + 33554432);
    bf16_t* img_b   = (bf16_t*)(ws + 117440512);
    bf16_t* conv_b  = (bf16_t*)(ws + 134217728);
    float*  ctxp    = (float*)(ws + 150994944);
    float*  ctx     = (float*)(ws + 153092096);
    bf16_t* WqkvT   = (bf16_t*)(ws + 153354240);
    bf16_t* WprojT  = (bf16_t*)(ws + 153747456);
    bf16_t* Wfc1T   = (bf16_t*)(ws + 153878528);
    bf16_t* Wfc2T   = (bf16_t*)(ws + 154927104);

    // ph1: x -> t (f32) + t_b (bf16); all weight casts upfront
    transpose_cast<0><<<dim3(N_ / 32, C_ / 32, B_), dim3(32, 8), 0, stream>>>(x, t, t_b);
    wcastT<<<dim3(768 / 32, C_ / 32), dim3(32, 8), 0, stream>>>(Wqkv, WqkvT, C_, 768);
    wcastT<<<dim3(C_ / 32, C_ / 32), dim3(32, 8), 0, stream>>>(Wproj, WprojT, C_, C_);
    wcastT<<<dim3(CM_ / 32, C_ / 32), dim3(32, 8), 0, stream>>>(Wfc1, Wfc1T, C_, CM_);
    wcastT<<<dim3(C_ / 32, CM_ / 32), dim3(32, 8), 0, stream>>>(Wfc2, Wfc2T, CM_, C_);

    // ph2: qkv_b = bf16(t @ Wqkv + bqkv)
    gemm_bf16<4><<<dim3(768 / 128, M_ / 128), 256, 0, stream>>>(
        t_b, WqkvT, bqkv, nullptr, qkv_b, M_, 768, C_,
        nullptr, nullptr, nullptr, nullptr, nullptr, nullptr, 0);

    // ph3: ctx = relu(k)^T v
    ctx_partial<<<dim3(8, B_ * NH_), 256, 0, stream>>>(qkv_b, ctxp);
    ctx_reduce<<<256, 256, 0, stream>>>(ctxp, ctx);

    // ph4: img_b = (relu(q)*scale) @ ctx   [B,C,N] bf16
    attn_out<<<dim3(N_ / 64, B_ * NH_), 256, 0, stream>>>(qkv_b, ctx, img_b);

    // ph5: depthwise conv (bf16 -> bf16)
    dwconv3x3<<<B_ * C_, 256, 0, stream>>>(img_b, dw_w, dw_b, conv_b);

    // ph6: conv_b -> convT_b (bf16 [B,N,C])
    transpose_cast<1><<<dim3(N_ / 32, C_ / 32, B_), dim3(32, 8), 0, stream>>>(conv_b, nullptr, convT_b);

    // ph7: t = repbn1(t + convT @ Wproj + bproj); t_b2 = bf16(t)
    gemm_bf16<1><<<dim3(C_ / 128, M_ / 128), 256, 0, stream>>>(
        convT_b, WprojT, bproj, t, t_b2, M_, C_, C_,
        t, bn1_g, bn1_b, bn1_m, bn1_v, alpha1, 0);

    // ph8/ph9: FFN in 2 chunks of 16384 rows
    constexpr int CHUNK = 16384;
    for (int ch = 0; ch < 2; ++ch) {
        const bf16_t* Arow = t_b2 + (size_t)ch * CHUNK * C_;
        gemm_bf16<2><<<dim3(CM_ / 128, CHUNK / 128), 256, 0, stream>>>(
            Arow, Wfc1T, bfc1, nullptr, hidden, CHUNK, CM_, C_,
            nullptr, nullptr, nullptr, nullptr, nullptr, nullptr, 0);
        gemm_bf16<3><<<dim3(C_ / 128, CHUNK / 128), 256, 0, stream>>>(
            hidden, Wfc2T, bfc2, out, nullptr, CHUNK, C_, CM_,
            t, bn2_g, bn2_b, bn2_m, bn2_v, alpha2, ch * CHUNK);
    }
}

// Round 4
// 349.769 us; speedup vs baseline: 4.1762x; 1.1866x over previous
//
#include <hip/hip_runtime.h>
#include <hip/hip_bf16.h>
#include <math.h>

// Problem constants
constexpr int B_ = 8, C_ = 256, H_ = 64, W_ = 64;
constexpr int N_ = H_ * W_;          // 4096
constexpr int NH_ = 8;
constexpr int CM_ = 2048;
constexpr int M_ = B_ * N_;          // 32768
constexpr float EPS_ = 1e-5f;

typedef __bf16 bf16_t;
typedef bf16_t bf16x8 __attribute__((ext_vector_type(8)));
typedef float f32x4 __attribute__((ext_vector_type(4)));

__device__ inline bf16_t f2b(float f) {
    __hip_bfloat16 h = __float2bfloat16(f);
    return *reinterpret_cast<bf16_t*>(&h);
}
__device__ inline float b2f(bf16_t b) {
    unsigned short u = *reinterpret_cast<unsigned short*>(&b);
    unsigned int x = (unsigned int)u << 16;
    return *reinterpret_cast<float*>(&x);
}

#define GLOAD_LDS16(gptr, lptr)                                                     \
    __builtin_amdgcn_global_load_lds(                                               \
        (const __attribute__((address_space(1))) void*)(gptr),                      \
        (__attribute__((address_space(3))) void*)(lptr), 16, 0, 0)

// ---------------------------------------------------------------------------
// Transpose [B,C,N] -> [B,N,C] (bf16 out).
// MODE 0: f32 in;  MODE 1: bf16 in.
template <int MODE>
__global__ void transpose_cast(const void* __restrict__ in_, bf16_t* __restrict__ outb) {
    __shared__ float tile[32][33];
    int b  = blockIdx.z;
    int n0 = blockIdx.x * 32;
    int c0 = blockIdx.y * 32;
    int tx = threadIdx.x, ty = threadIdx.y;
#pragma unroll
    for (int i = ty; i < 32; i += 8) {
        size_t off = (size_t)b * C_ * N_ + (size_t)(c0 + i) * N_ + n0 + tx;
        tile[i][tx] = (MODE == 0) ? ((const float*)in_)[off] : b2f(((const bf16_t*)in_)[off]);
    }
    __syncthreads();
#pragma unroll
    for (int i = ty; i < 32; i += 8) {
        size_t off = (size_t)b * N_ * C_ + (size_t)(n0 + i) * C_ + c0 + tx;
        outb[off] = f2b(tile[tx][i]);
    }
}

// ---------------------------------------------------------------------------
// Weight cast + transpose: W [K,N] f32 -> Wt [N,K] bf16
__global__ void wcastT(const float* __restrict__ W, bf16_t* __restrict__ Wt,
                       int K, int N) {
    __shared__ float tile[32][33];
    int k0 = blockIdx.y * 32, n0 = blockIdx.x * 32;
    int tx = threadIdx.x, ty = threadIdx.y;
#pragma unroll
    for (int i = ty; i < 32; i += 8)
        tile[i][tx] = W[(size_t)(k0 + i) * N + n0 + tx];
    __syncthreads();
#pragma unroll
    for (int i = ty; i < 32; i += 8)
        Wt[(size_t)(n0 + i) * K + k0 + tx] = f2b(tile[tx][i]);
}

// ---------------------------------------------------------------------------
// bf16 MFMA GEMM: C = A[M,K] @ Bt[N,K]^T + bias, fused epilogues.
// 128x128 tile, BK=64, 4 waves (each 64x64 out via 4x4 frags of 16x16x32).
// EPI 1: z=b2f(tres_b)+acc+bias; repbn1 -> Cb (bf16)
// EPI 2: gelu_approx(acc+bias) -> Cb (bf16)
// EPI 3: z=b2f(tres_b[grow])+acc+bias; repbn2 -> Cf transposed to [B,C,N] (f32)
// EPI 4: acc+bias -> Cb (bf16)
template <int EPI>
__global__ __launch_bounds__(256)
void gemm_bf16(const bf16_t* __restrict__ A, const bf16_t* __restrict__ Bt,
               const float* __restrict__ bias,
               float* __restrict__ Cf, bf16_t* __restrict__ Cb,
               int M, int N, int K,
               const bf16_t* __restrict__ tres_b,
               const float* __restrict__ g, const float* __restrict__ bb,
               const float* __restrict__ mm, const float* __restrict__ vv,
               const float* __restrict__ alpha, int row_off) {
    __shared__ bf16x8 ldsv[2048];          // 32 KB: A = [0,1024), B = [1024,2048)
    char* lds = (char*)ldsv;

    int tid  = threadIdx.x;
    int lane = tid & 63;
    int w    = tid >> 6;
    int wm   = w >> 1, wn = w & 1;
    int brow = blockIdx.y * 128, bcol = blockIdx.x * 128;
    int rowl = lane & 15, kq = lane >> 4;

    f32x4 acc[4][4] = {};

    for (int k0 = 0; k0 < K; k0 += 64) {
#pragma unroll
        for (int j = 0; j < 4; ++j) {
            int jj = w * 4 + j;
            int msub = jj >> 1, kh = jj & 1;
            const bf16_t* ga = A + ((size_t)(brow + msub * 16 + rowl) * K + k0 + kh * 32 + kq * 8);
            GLOAD_LDS16(ga, lds + jj * 1024);
            const bf16_t* gb = Bt + ((size_t)(bcol + msub * 16 + rowl) * K + k0 + kh * 32 + kq * 8);
            GLOAD_LDS16(gb, lds + 16384 + jj * 1024);
        }
        __syncthreads();
#pragma unroll
        for (int ks = 0; ks < 2; ++ks) {
            bf16x8 af[4], bfr[4];
#pragma unroll
            for (int m = 0; m < 4; ++m) af[m] = ldsv[((wm * 4 + m) * 2 + ks) * 64 + lane];
#pragma unroll
            for (int n = 0; n < 4; ++n) bfr[n] = ldsv[1024 + ((wn * 4 + n) * 2 + ks) * 64 + lane];
#pragma unroll
            for (int m = 0; m < 4; ++m)
#pragma unroll
                for (int n = 0; n < 4; ++n)
                    acc[m][n] = __builtin_amdgcn_mfma_f32_16x16x32_bf16(af[m], bfr[n], acc[m][n], 0, 0, 0);
        }
        __syncthreads();
    }

    float alpha_v = (EPI == 1 || EPI == 3) ? alpha[0] : 0.f;
#pragma unroll
    for (int m = 0; m < 4; ++m) {
#pragma unroll
        for (int n = 0; n < 4; ++n) {
            int col = bcol + wn * 64 + n * 16 + (lane & 15);
            float bv = bias[col];
#pragma unroll
            for (int r = 0; r < 4; ++r) {
                int row = brow + wm * 64 + m * 16 + (lane >> 4) * 4 + r;
                float y = acc[m][n][r] + bv;
                if (EPI == 4) {
                    Cb[(size_t)row * N + col] = f2b(y);
                } else if (EPI == 2) {
                    // gelu(y) ~= y - y / (exp(2u)+1), u = y*(c1 + c3*y^2)
                    float u = y * (0.7978845608f + 0.0356774081f * y * y);
                    float e = __expf(2.0f * u);
                    float ge = y - y * __builtin_amdgcn_rcpf(e + 1.0f);
                    Cb[(size_t)row * N + col] = f2b(ge);
                } else if (EPI == 1) {
                    float z = b2f(tres_b[(size_t)row * N + col]) + y;
                    float rr = (z - mm[col]) * rsqrtf(vv[col] + EPS_) * g[col] + bb[col] + alpha_v * z;
                    Cb[(size_t)row * N + col] = f2b(rr);
                } else {  // EPI 3
                    int grow = row_off + row;
                    float z = b2f(tres_b[(size_t)grow * C_ + col]) + y;
                    float rr = (z - mm[col]) * rsqrtf(vv[col] + EPS_) * g[col] + bb[col] + alpha_v * z;
                    int bi = grow >> 12, ni = grow & (N_ - 1);
                    Cf[((size_t)bi * C_ + col) * N_ + ni] = rr;
                }
            }
        }
    }
}

// ---------------------------------------------------------------------------
// ctx partials: ctxp[seg][b*NH+h][d][e] = sum_{n in seg} relu(k[n,d]) * v[n,e]
// qkv is bf16 [B,N,768]
__global__ void ctx_partial(const bf16_t* __restrict__ qkv, float* __restrict__ ctxp) {
    __shared__ float kb[64][40];
    __shared__ float vb[64][40];
    int seg = blockIdx.x;
    int bh  = blockIdx.y;
    int b = bh >> 3, h = bh & 7;
    int tid = threadIdx.x;
    int d  = tid >> 3;
    int e0 = (tid & 7) * 4;
    int lrow = tid >> 2, lcol = (tid & 3) * 8;
    float acc[4] = {0.f, 0.f, 0.f, 0.f};
    const size_t base = (size_t)b * N_ * 768 + h * 32;
    for (int n0 = seg * 512; n0 < seg * 512 + 512; n0 += 64) {
        size_t ra = base + (size_t)(n0 + lrow) * 768 + lcol;
        bf16x8 kv8 = *(const bf16x8*)(qkv + ra + 256);
        bf16x8 vv8 = *(const bf16x8*)(qkv + ra + 512);
#pragma unroll
        for (int j = 0; j < 8; ++j) {
            kb[lrow][lcol + j] = b2f(kv8[j]);
            vb[lrow][lcol + j] = b2f(vv8[j]);
        }
        __syncthreads();
#pragma unroll
        for (int nl = 0; nl < 64; ++nl) {
            float kv = fmaxf(kb[nl][d], 0.f);
#pragma unroll
            for (int j = 0; j < 4; ++j)
                acc[j] = fmaf(kv, vb[nl][e0 + j], acc[j]);
        }
        __syncthreads();
    }
    float* o = ctxp + ((size_t)seg * 64 + bh) * 1024 + d * 32 + e0;
#pragma unroll
    for (int j = 0; j < 4; ++j) o[j] = acc[j];
}

__global__ void ctx_reduce(const float* __restrict__ ctxp, float* __restrict__ ctx) {
    int idx = blockIdx.x * 256 + threadIdx.x;
    float s = 0.f;
#pragma unroll
    for (int seg = 0; seg < 8; ++seg) s += ctxp[(size_t)seg * 65536 + idx];
    ctx[idx] = s;
}

// ---------------------------------------------------------------------------
// img[b, h*32+e, n] = sum_d relu(q[n,d])*scale * ctx[bh][d][e]   (bf16 out)
__global__ void attn_out(const bf16_t* __restrict__ qkv, const float* __restrict__ ctx,
                         bf16_t* __restrict__ img) {
    __shared__ float qb[64][33];
    __shared__ float cs[32][32];
    int n0 = blockIdx.x * 64;
    int bh = blockIdx.y;
    int b = bh >> 3, h = bh & 7;
    int tid = threadIdx.x;
    const float scale = 0.17677669529663687f;
    {
        float4 vv = ((const float4*)(ctx + (size_t)bh * 1024))[tid];
        ((float4*)&cs[0][0])[tid] = vv;
    }
    const size_t base = (size_t)b * N_ * 768 + h * 32;
    int lrow = tid >> 2, lcol = (tid & 3) * 8;
    {
        bf16x8 q8 = *(const bf16x8*)(qkv + base + (size_t)(n0 + lrow) * 768 + lcol);
#pragma unroll
        for (int j = 0; j < 8; ++j)
            qb[lrow][lcol + j] = fmaxf(b2f(q8[j]), 0.f) * scale;
    }
    __syncthreads();
    int nl = tid & 63, ebase = tid >> 6;
    bf16_t* outp = img + ((size_t)b * C_ + h * 32) * N_ + n0 + nl;
#pragma unroll
    for (int p = 0; p < 8; ++p) {
        int e = ebase + p * 4;
        float s = 0.f;
#pragma unroll
        for (int dd = 0; dd < 32; ++dd)
            s = fmaf(qb[nl][dd], cs[dd][e], s);
        outp[(size_t)e * N_] = f2b(s);
    }
}

// ---------------------------------------------------------------------------
// depthwise 3x3 SAME conv + bias. One block per (b,c) plane (64x64), bf16 io.
__global__ __launch_bounds__(256)
void dwconv3x3(const bf16_t* __restrict__ img, const float* __restrict__ w,
               const float* __restrict__ bias, bf16_t* __restrict__ out) {
    __shared__ float sp[64][65];
    int bc = blockIdx.x;            // b*C + c
    int c  = bc & 255;
    int tid = threadIdx.x;
    const bf16_t* ip = img + (size_t)bc * N_;
#pragma unroll
    for (int l = 0; l < 2; ++l) {
        int flat = (tid + l * 256) * 8;
        int row = flat >> 6, col = flat & 63;
        bf16x8 v8 = *(const bf16x8*)(ip + flat);
#pragma unroll
        for (int j = 0; j < 8; ++j) sp[row][col + j] = b2f(v8[j]);
    }
    float wv[9];
#pragma unroll
    for (int j = 0; j < 9; ++j) wv[j] = w[c * 9 + j];
    float bv = bias[c];
    __syncthreads();

    int y = tid >> 2, x0 = (tid & 3) * 16;
    float o[16];
#pragma unroll
    for (int i = 0; i < 16; ++i) o[i] = bv;
#pragma unroll
    for (int dy = -1; dy <= 1; ++dy) {
        int yy = y + dy;
        if (yy < 0 || yy > 63) continue;
#pragma unroll
        for (int dx = -1; dx <= 1; ++dx) {
            float wgt = wv[(dy + 1) * 3 + dx + 1];
#pragma unroll
            for (int i = 0; i < 16; ++i) {
                int xx = x0 + i + dx;
                float val = (xx < 0 || xx > 63) ? 0.f : sp[yy][xx];
                o[i] = fmaf(wgt, val, o[i]);
            }
        }
    }
    bf16_t ob[16];
#pragma unroll
    for (int i = 0; i < 16; ++i) ob[i] = f2b(o[i]);
    *(bf16x8*)(out + (size_t)bc * N_ + y * 64 + x0)     = *(bf16x8*)&ob[0];
    *(bf16x8*)(out + (size_t)bc * N_ + y * 64 + x0 + 8) = *(bf16x8*)&ob[8];
}

// ---------------------------------------------------------------------------
extern "C" void kernel_launch(void* const* d_in, const int* in_sizes, int n_in,
                              void* d_out, int out_size, void* d_ws, size_t ws_size,
                              hipStream_t stream) {
    const float* x     = (const float*)d_in[0];
    const float* Wqkv  = (const float*)d_in[1];
    const float* bqkv  = (const float*)d_in[2];
    const float* dw_w  = (const float*)d_in[3];
    const float* dw_b  = (const float*)d_in[4];
    const float* Wproj = (const float*)d_in[5];
    const float* bproj = (const float*)d_in[6];
    const float* bn1_g = (const float*)d_in[7];
    const float* bn1_b = (const float*)d_in[8];
    const float* bn1_m = (const float*)d_in[9];
    const float* bn1_v = (const float*)d_in[10];
    const float* alpha1= (const float*)d_in[11];
    const float* Wfc1  = (const float*)d_in[12];
    const float* bfc1  = (const float*)d_in[13];
    const float* Wfc2  = (const float*)d_in[14];
    const float* bfc2  = (const float*)d_in[15];
    const float* bn2_g = (const float*)d_in[16];
    const float* bn2_b = (const float*)d_in[17];
    const float* bn2_m = (const float*)d_in[18];
    const float* bn2_v = (const float*)d_in[19];
    const float* alpha2= (const float*)d_in[20];
    float* out = (float*)d_out;

    char* ws = (char*)d_ws;
    // Workspace layout (bytes), peak 155,975,680 <= proven 170,131,456:
    //   t_b2    @ 0            16,777,216  bf16 [B,N,C]      (ph7..ph9)
    //   WqkvT   @ 16,777,216      393,216  bf16
    //   WprojT  @ 17,170,432      131,072  bf16
    //   Wfc1T   @ 17,301,504    1,048,576  bf16
    //   Wfc2T   @ 18,350,080    1,048,576  bf16
    //   ctxp    @ 19,398,656    2,097,152  f32               (ph3)
    //   ctx     @ 21,495,808      262,144  f32               (ph3..ph4)
    //   t_b     @ 21,757,952   16,777,216  bf16 [B,N,C]      (ph1..ph7)
    //   qkv_b   @ 38,535,168   50,331,648  bf16 [B,N,768]    (ph2..ph4)
    //   img_b   @ 88,866,816   16,777,216  bf16 [B,C,N]      (ph4..ph5)
    //   conv_b  @ 105,644,032  16,777,216  bf16 [B,C,N]      (ph5..ph6)
    //   convT_b @ 122,421,248  16,777,216  bf16 [B,N,C]      (ph6..ph7)
    //   hidden  @ 21,757,952  134,217,728  bf16 [M,CM]       (ph8..ph9; over dead ph1-7 bufs)
    bf16_t* t_b2    = (bf16_t*)(ws);
    bf16_t* WqkvT   = (bf16_t*)(ws + 16777216);
    bf16_t* WprojT  = (bf16_t*)(ws + 17170432);
    bf16_t* Wfc1T   = (bf16_t*)(ws + 17301504);
    bf16_t* Wfc2T   = (bf16_t*)(ws + 18350080);
    float*  ctxp    = (float*)(ws + 19398656);
    float*  ctx     = (float*)(ws + 21495808);
    bf16_t* t_b     = (bf16_t*)(ws + 21757952);
    bf16_t* qkv_b   = (bf16_t*)(ws + 38535168);
    bf16_t* img_b   = (bf16_t*)(ws + 88866816);
    bf16_t* conv_b  = (bf16_t*)(ws + 105644032);
    bf16_t* convT_b = (bf16_t*)(ws + 122421248);
    bf16_t* hidden  = (bf16_t*)(ws + 21757952);

    // ph1: x -> t_b (bf16); weight casts
    transpose_cast<0><<<dim3(N_ / 32, C_ / 32, B_), dim3(32, 8), 0, stream>>>(x, t_b);
    wcastT<<<dim3(768 / 32, C_ / 32), dim3(32, 8), 0, stream>>>(Wqkv, WqkvT, C_, 768);
    wcastT<<<dim3(C_ / 32, C_ / 32), dim3(32, 8), 0, stream>>>(Wproj, WprojT, C_, C_);
    wcastT<<<dim3(CM_ / 32, C_ / 32), dim3(32, 8), 0, stream>>>(Wfc1, Wfc1T, C_, CM_);
    wcastT<<<dim3(C_ / 32, CM_ / 32), dim3(32, 8), 0, stream>>>(Wfc2, Wfc2T, CM_, C_);

    // ph2: qkv_b = bf16(t @ Wqkv + bqkv)
    gemm_bf16<4><<<dim3(768 / 128, M_ / 128), 256, 0, stream>>>(
        t_b, WqkvT, bqkv, nullptr, qkv_b, M_, 768, C_,
        nullptr, nullptr, nullptr, nullptr, nullptr, nullptr, 0);

    // ph3: ctx = relu(k)^T v
    ctx_partial<<<dim3(8, B_ * NH_), 256, 0, stream>>>(qkv_b, ctxp);
    ctx_reduce<<<256, 256, 0, stream>>>(ctxp, ctx);

    // ph4: img_b = (relu(q)*scale) @ ctx   [B,C,N] bf16
    attn_out<<<dim3(N_ / 64, B_ * NH_), 256, 0, stream>>>(qkv_b, ctx, img_b);

    // ph5: depthwise conv (bf16 -> bf16)
    dwconv3x3<<<B_ * C_, 256, 0, stream>>>(img_b, dw_w, dw_b, conv_b);

    // ph6: conv_b -> convT_b (bf16 [B,N,C])
    transpose_cast<1><<<dim3(N_ / 32, C_ / 32, B_), dim3(32, 8), 0, stream>>>(conv_b, convT_b);

    // ph7: t_b2 = repbn1(t_b + convT @ Wproj + bproj)   (bf16)
    gemm_bf16<1><<<dim3(C_ / 128, M_ / 128), 256, 0, stream>>>(
        convT_b, WprojT, bproj, nullptr, t_b2, M_, C_, C_,
        t_b, bn1_g, bn1_b, bn1_m, bn1_v, alpha1, 0);

    // ph8: hidden = gelu(t_b2 @ Wfc1 + bfc1)   (full M)
    gemm_bf16<2><<<dim3(CM_ / 128, M_ / 128), 256, 0, stream>>>(
        t_b2, Wfc1T, bfc1, nullptr, hidden, M_, CM_, C_,
        nullptr, nullptr, nullptr, nullptr, nullptr, nullptr, 0);

    // ph9: out = repbn2(t_b2 + hidden @ Wfc2 + bfc2), transposed to [B,C,H,W]
    gemm_bf16<3><<<dim3(C_ / 128, M_ / 128), 256, 0, stream>>>(
        hidden, Wfc2T, bfc2, out, nullptr, M_, C_, CM_,
        t_b2, bn2_g, bn2_b, bn2_m, bn2_v, alpha2, 0);
}